// Round 1
// baseline (437.505 us; speedup 1.0000x reference)
//
#include <hip/hip_runtime.h>
#include <hip/hip_bf16.h>
#include <math.h>

// Problem constants
static constexpr int NB    = 2048;  // batch
static constexpr int NPOOL = 512;   // e_prompt_pool_size
static constexpr int NTOPK = 4;     // top_k
static constexpr int NEPL  = 8;     // e_prompt_length
static constexpr int NEMB  = 768;   // emb_d / key_dim
static constexpr int NSLOT = 20;    // K*EPL/2 + GPL/2 = 16 + 4

// ---------------------------------------------------------------------------
// Row L2 norms (fp64): rows 0..NB-1 -> x_querry, rows NB..NB+NPOOL-1 -> e_k
// ---------------------------------------------------------------------------
__global__ __launch_bounds__(256) void norms_kernel(
    const float* __restrict__ xq, const float* __restrict__ ek,
    double* __restrict__ qn, double* __restrict__ kn) {
  int row = blockIdx.x;
  const float* src;
  double* dst;
  if (row < NB) { src = xq + (size_t)row * NEMB; dst = qn + row; }
  else          { src = ek + (size_t)(row - NB) * NEMB; dst = kn + (row - NB); }
  double s = 0.0;
  for (int i = threadIdx.x; i < NEMB; i += 256) {
    double v = (double)src[i];
    s += v * v;
  }
  for (int off = 32; off > 0; off >>= 1) s += __shfl_down(s, off, 64);
  __shared__ double red[4];
  if ((threadIdx.x & 63) == 0) red[threadIdx.x >> 6] = s;
  __syncthreads();
  if (threadIdx.x == 0) *dst = sqrt(red[0] + red[1] + red[2] + red[3]);
}

// ---------------------------------------------------------------------------
// cos_sim[b][p] = (xq[b].ek[p]) / (max(|xq[b]|,eps)*max(|ek[p]|,eps))  (fp64)
// 32x32 tile per 256-thread block, 2x2 per thread, fp64 accumulation.
// ---------------------------------------------------------------------------
__global__ __launch_bounds__(256) void cos_kernel(
    const float* __restrict__ xq, const float* __restrict__ ek,
    const double* __restrict__ qn, const double* __restrict__ kn,
    double* __restrict__ cosm) {
  __shared__ double As[32][33];
  __shared__ double Bs[32][33];
  const int tid = threadIdx.x;
  const int tx = tid & 15;   // p-dir (2 cols each)
  const int ty = tid >> 4;   // b-dir (2 rows each)
  const int bp = blockIdx.x * 32;
  const int bb = blockIdx.y * 32;
  const int lrow = tid >> 3;        // 0..31
  const int lc4  = (tid & 7) * 4;   // 0..28 step 4
  double acc00 = 0, acc01 = 0, acc10 = 0, acc11 = 0;
  for (int k0 = 0; k0 < NEMB; k0 += 32) {
    float4 a  = *(const float4*)(xq + (size_t)(bb + lrow) * NEMB + k0 + lc4);
    float4 bv = *(const float4*)(ek + (size_t)(bp + lrow) * NEMB + k0 + lc4);
    As[lrow][lc4 + 0] = (double)a.x;  As[lrow][lc4 + 1] = (double)a.y;
    As[lrow][lc4 + 2] = (double)a.z;  As[lrow][lc4 + 3] = (double)a.w;
    Bs[lrow][lc4 + 0] = (double)bv.x; Bs[lrow][lc4 + 1] = (double)bv.y;
    Bs[lrow][lc4 + 2] = (double)bv.z; Bs[lrow][lc4 + 3] = (double)bv.w;
    __syncthreads();
#pragma unroll
    for (int kk = 0; kk < 32; kk++) {
      double a0 = As[ty * 2][kk],  a1 = As[ty * 2 + 1][kk];
      double b0 = Bs[tx * 2][kk],  b1 = Bs[tx * 2 + 1][kk];
      acc00 = fma(a0, b0, acc00);  acc01 = fma(a0, b1, acc01);
      acc10 = fma(a1, b0, acc10);  acc11 = fma(a1, b1, acc11);
    }
    __syncthreads();
  }
  int b0 = bb + ty * 2, p0 = bp + tx * 2;
  double dq0 = fmax(qn[b0], 1e-12),     dq1 = fmax(qn[b0 + 1], 1e-12);
  double dp0 = fmax(kn[p0], 1e-12),     dp1 = fmax(kn[p0 + 1], 1e-12);
  cosm[(size_t)b0 * NPOOL + p0]           = acc00 / (dq0 * dp0);
  cosm[(size_t)b0 * NPOOL + p0 + 1]       = acc01 / (dq0 * dp1);
  cosm[(size_t)(b0 + 1) * NPOOL + p0]     = acc10 / (dq1 * dp0);
  cosm[(size_t)(b0 + 1) * NPOOL + p0 + 1] = acc11 / (dq1 * dp1);
}

// ---------------------------------------------------------------------------
// Top-4 (largest cos == smallest distance), tie -> lower index.
// One wave per row; per-lane insertion then xor-butterfly 4-list merge.
// ---------------------------------------------------------------------------
__device__ __forceinline__ bool tk_better(double av, int ai, double bv, int bi) {
  return (av > bv) || (av == bv && ai < bi);
}

__global__ __launch_bounds__(256) void topk_kernel(
    const double* __restrict__ cosm, int* __restrict__ kidx,
    int* __restrict__ counts) {
  int wave = threadIdx.x >> 6, lane = threadIdx.x & 63;
  int row = blockIdx.x * 4 + wave;
  const double* crow = cosm + (size_t)row * NPOOL;
  double v[4] = {-1e300, -1e300, -1e300, -1e300};
  int vi[4] = {0x7fffffff, 0x7fffffff, 0x7fffffff, 0x7fffffff};
#pragma unroll
  for (int j = 0; j < 8; j++) {
    int p = j * 64 + lane;
    double x = crow[p];
    if (x > v[3]) {
      if (x > v[0]) {
        v[3]=v[2]; vi[3]=vi[2]; v[2]=v[1]; vi[2]=vi[1]; v[1]=v[0]; vi[1]=vi[0];
        v[0]=x; vi[0]=p;
      } else if (x > v[1]) {
        v[3]=v[2]; vi[3]=vi[2]; v[2]=v[1]; vi[2]=vi[1]; v[1]=x; vi[1]=p;
      } else if (x > v[2]) {
        v[3]=v[2]; vi[3]=vi[2]; v[2]=x; vi[2]=p;
      } else {
        v[3]=x; vi[3]=p;
      }
    }
  }
#pragma unroll
  for (int off = 1; off < 64; off <<= 1) {
    double ov[4]; int oi[4];
#pragma unroll
    for (int m = 0; m < 4; m++) {
      ov[m] = __shfl_xor(v[m], off, 64);
      oi[m] = __shfl_xor(vi[m], off, 64);
    }
    double mv[4]; int mi[4];
    int ia = 0, ib = 0;
#pragma unroll
    for (int m = 0; m < 4; m++) {
      if (tk_better(v[ia], vi[ia], ov[ib], oi[ib])) { mv[m]=v[ia]; mi[m]=vi[ia]; ia++; }
      else                                          { mv[m]=ov[ib]; mi[m]=oi[ib]; ib++; }
    }
#pragma unroll
    for (int m = 0; m < 4; m++) { v[m] = mv[m]; vi[m] = mi[m]; }
  }
  if (lane == 0) {
#pragma unroll
    for (int m = 0; m < 4; m++) {
      kidx[row * 4 + m] = vi[m];
      atomicAdd(&counts[vi[m]], 1);
    }
  }
}

// ---------------------------------------------------------------------------
// Column sums S[p] = sum_b cos[b][p] (fp64, atomics across row-chunks)
// ---------------------------------------------------------------------------
__global__ __launch_bounds__(256) void colsum_kernel(
    const double* __restrict__ cosm, double* __restrict__ S) {
  int p = blockIdx.x * 256 + threadIdx.x;
  int r0 = blockIdx.y * 128;
  double s = 0.0;
  for (int r = r0; r < r0 + 128; r++) s += cosm[(size_t)r * NPOOL + p];
  atomicAdd(&S[p], s);
}

// ---------------------------------------------------------------------------
// loss = 1 - (sum_p counts[p]*S[p]) / (B*B*K); also emit counts as float
// ---------------------------------------------------------------------------
__global__ __launch_bounds__(256) void loss_counts_kernel(
    const double* __restrict__ S, const int* __restrict__ counts,
    float* __restrict__ out_loss, float* __restrict__ out_counts) {
  double s = 0.0;
  for (int p = threadIdx.x; p < NPOOL; p += 256) {
    int c = counts[p];
    out_counts[p] = (float)c;
    s += (double)c * S[p];
  }
  for (int off = 32; off > 0; off >>= 1) s += __shfl_down(s, off, 64);
  __shared__ double red[4];
  if ((threadIdx.x & 63) == 0) red[threadIdx.x >> 6] = s;
  __syncthreads();
  if (threadIdx.x == 0) {
    double total = red[0] + red[1] + red[2] + red[3];
    *out_loss = (float)(1.0 - total / (double)((long long)NB * NB * NTOPK));
  }
}

// ---------------------------------------------------------------------------
// Gather Pk/Pv: slot s<16 -> e_p[idx[s/4]][s%4 (+4 for Pv)]; s>=16 -> g_p
// One block per batch row; float4 copies, fully coalesced.
// ---------------------------------------------------------------------------
__global__ __launch_bounds__(256) void gather_kernel(
    const float* __restrict__ e_p, const float* __restrict__ g_p,
    const int* __restrict__ kidx, float* __restrict__ Pk,
    float* __restrict__ Pv) {
  int b = blockIdx.x;
  __shared__ int idx[4];
  if (threadIdx.x < 4) idx[threadIdx.x] = kidx[b * 4 + threadIdx.x];
  __syncthreads();
  float4* dk = (float4*)(Pk + (size_t)b * NSLOT * NEMB);
  float4* dv = (float4*)(Pv + (size_t)b * NSLOT * NEMB);
  const int R = NEMB / 4;  // 192 float4 per row
  for (int u = threadIdx.x; u < NSLOT * R; u += 256) {
    int s = u / R;
    int r = u - s * R;
    const float4* sk;
    const float4* sv;
    if (s < 16) {
      int pi = idx[s >> 2];
      int t = s & 3;
      const float* basek = e_p + ((size_t)pi * NEPL + t) * NEMB;
      sk = (const float4*)basek;
      sv = (const float4*)(basek + 4 * NEMB);
    } else {
      sk = (const float4*)(g_p + (size_t)(s - 16) * NEMB);
      sv = (const float4*)(g_p + (size_t)(s - 16 + 4) * NEMB);
    }
    dk[u] = sk[r];
    dv[u] = sv[r];
  }
}

// ---------------------------------------------------------------------------
// x_block passthrough (dst not 16B-aligned: 62,915,073 floats offset -> scalar)
// ---------------------------------------------------------------------------
__global__ __launch_bounds__(256) void copy_kernel(
    const float* __restrict__ src, float* __restrict__ dst, int n) {
  int i = blockIdx.x * 256 + threadIdx.x;
  int stride = gridDim.x * 256;
  for (; i < n; i += stride) dst[i] = src[i];
}

extern "C" void kernel_launch(void* const* d_in, const int* in_sizes, int n_in,
                              void* d_out, int out_size, void* d_ws, size_t ws_size,
                              hipStream_t stream) {
  const float* x_querry = (const float*)d_in[0];
  const float* x_block  = (const float*)d_in[1];
  const float* e_k      = (const float*)d_in[2];
  const float* e_p      = (const float*)d_in[3];
  const float* g_p      = (const float*)d_in[4];
  // d_in[5] = l (scalar 0) — both E- and G-branches always taken.

  // Workspace layout (~8.5 MB)
  double* qn     = (double*)d_ws;                    // 2048
  double* kn     = qn + NB;                          // 512
  double* S      = kn + NPOOL;                       // 512
  double* cosm   = S + NPOOL;                        // 2048*512
  int*    kidx   = (int*)(cosm + (size_t)NB * NPOOL);// 8192
  int*    counts = kidx + NB * NTOPK;                // 512

  // Output layout (floats): Pk | Pv | loss | counts | x_block
  float* out        = (float*)d_out;
  float* Pk         = out;
  float* Pv         = Pk + (size_t)NB * NSLOT * NEMB;
  float* out_loss   = Pv + (size_t)NB * NSLOT * NEMB;
  float* out_counts = out_loss + 1;
  float* out_xb     = out_counts + NPOOL;

  hipMemsetAsync(S, 0, NPOOL * sizeof(double), stream);
  hipMemsetAsync(counts, 0, NPOOL * sizeof(int), stream);

  norms_kernel<<<NB + NPOOL, 256, 0, stream>>>(x_querry, e_k, qn, kn);
  cos_kernel<<<dim3(NPOOL / 32, NB / 32), 256, 0, stream>>>(x_querry, e_k, qn, kn, cosm);
  topk_kernel<<<NB / 4, 256, 0, stream>>>(cosm, kidx, counts);
  colsum_kernel<<<dim3(NPOOL / 256, NB / 128), 256, 0, stream>>>(cosm, S);
  loss_counts_kernel<<<1, 256, 0, stream>>>(S, counts, out_loss, out_counts);
  gather_kernel<<<NB, 256, 0, stream>>>(e_p, g_p, kidx, Pk, Pv);
  copy_kernel<<<1024, 256, 0, stream>>>(x_block, out_xb, NB * NEMB);
}

// Round 2
// 381.865 us; speedup vs baseline: 1.1457x; 1.1457x over previous
//
#include <hip/hip_runtime.h>
#include <hip/hip_bf16.h>
#include <math.h>

// Problem constants
static constexpr int NB    = 2048;  // batch
static constexpr int NPOOL = 512;   // e_prompt_pool_size
static constexpr int NTOPK = 4;     // top_k
static constexpr int NEPL  = 8;     // e_prompt_length
static constexpr int NEMB  = 768;   // emb_d / key_dim
static constexpr int NSLOT = 20;    // K*EPL/2 + GPL/2 = 16 + 4
static constexpr int NCAND = 8;     // fp32 candidate pool, refined in fp64

// ---------------------------------------------------------------------------
// Row L2 norms: fp64 norms (for the fp64 rescoring) + fp32 reciprocals
// (for the fp32 GEMM epilogue). rows 0..NB-1 -> x_querry, rest -> e_k.
// ---------------------------------------------------------------------------
__global__ __launch_bounds__(256) void norms_kernel(
    const float* __restrict__ xq, const float* __restrict__ ek,
    double* __restrict__ qn, double* __restrict__ kn,
    float* __restrict__ rqn, float* __restrict__ rkn) {
  int row = blockIdx.x;
  const float* src;
  double* dst;
  float* rdst;
  if (row < NB) { src = xq + (size_t)row * NEMB; dst = qn + row; rdst = rqn + row; }
  else          { src = ek + (size_t)(row - NB) * NEMB; dst = kn + (row - NB); rdst = rkn + (row - NB); }
  double s = 0.0;
  for (int i = threadIdx.x; i < NEMB; i += 256) {
    double v = (double)src[i];
    s += v * v;
  }
  for (int off = 32; off > 0; off >>= 1) s += __shfl_down(s, off, 64);
  __shared__ double red[4];
  if ((threadIdx.x & 63) == 0) red[threadIdx.x >> 6] = s;
  __syncthreads();
  if (threadIdx.x == 0) {
    double n = sqrt(red[0] + red[1] + red[2] + red[3]);
    *dst = n;
    *rdst = (float)(1.0 / fmax(n, 1e-12));
  }
}

// ---------------------------------------------------------------------------
// fp32 cos GEMM: cosm[b][p] = (xq[b].ek[p]) * rqn[b] * rkn[p]
// 64x64 tile / block (256 thr, 4x4 per thread), BK=32, k-major LDS layout
// (As[k][m], stride 68 -> 16B-aligned rows, conflict-light b128 reads).
// ---------------------------------------------------------------------------
__global__ __launch_bounds__(256) void cos_kernel(
    const float* __restrict__ xq, const float* __restrict__ ek,
    const float* __restrict__ rqn, const float* __restrict__ rkn,
    float* __restrict__ cosm) {
  __shared__ float As[32][68];
  __shared__ float Bs[32][68];
  const int t = threadIdx.x;
  const int tx = t & 15;   // p-dir, 4 cols each
  const int ty = t >> 4;   // b-dir, 4 rows each
  const int bp = blockIdx.x * 64;
  const int bb = blockIdx.y * 64;
  float acc[4][4] = {};
  for (int k0 = 0; k0 < NEMB; k0 += 32) {
#pragma unroll
    for (int uu = 0; uu < 2; uu++) {
      int u = t + uu * 256;          // 0..511
      int m = u >> 3;                // 0..63
      int k4 = (u & 7) * 4;          // 0..28
      float4 a = *(const float4*)(xq + (size_t)(bb + m) * NEMB + k0 + k4);
      float4 b = *(const float4*)(ek + (size_t)(bp + m) * NEMB + k0 + k4);
      As[k4 + 0][m] = a.x; As[k4 + 1][m] = a.y; As[k4 + 2][m] = a.z; As[k4 + 3][m] = a.w;
      Bs[k4 + 0][m] = b.x; Bs[k4 + 1][m] = b.y; Bs[k4 + 2][m] = b.z; Bs[k4 + 3][m] = b.w;
    }
    __syncthreads();
#pragma unroll
    for (int kk = 0; kk < 32; kk++) {
      float4 av = *(const float4*)&As[kk][ty * 4];
      float4 bv = *(const float4*)&Bs[kk][tx * 4];
      acc[0][0] = fmaf(av.x, bv.x, acc[0][0]); acc[0][1] = fmaf(av.x, bv.y, acc[0][1]);
      acc[0][2] = fmaf(av.x, bv.z, acc[0][2]); acc[0][3] = fmaf(av.x, bv.w, acc[0][3]);
      acc[1][0] = fmaf(av.y, bv.x, acc[1][0]); acc[1][1] = fmaf(av.y, bv.y, acc[1][1]);
      acc[1][2] = fmaf(av.y, bv.z, acc[1][2]); acc[1][3] = fmaf(av.y, bv.w, acc[1][3]);
      acc[2][0] = fmaf(av.z, bv.x, acc[2][0]); acc[2][1] = fmaf(av.z, bv.y, acc[2][1]);
      acc[2][2] = fmaf(av.z, bv.z, acc[2][2]); acc[2][3] = fmaf(av.z, bv.w, acc[2][3]);
      acc[3][0] = fmaf(av.w, bv.x, acc[3][0]); acc[3][1] = fmaf(av.w, bv.y, acc[3][1]);
      acc[3][2] = fmaf(av.w, bv.z, acc[3][2]); acc[3][3] = fmaf(av.w, bv.w, acc[3][3]);
    }
    __syncthreads();
  }
  float4 rk = *(const float4*)&rkn[bp + tx * 4];
#pragma unroll
  for (int i = 0; i < 4; i++) {
    float rq = rqn[bb + ty * 4 + i];
    float4 cv;
    cv.x = acc[i][0] * rq * rk.x;
    cv.y = acc[i][1] * rq * rk.y;
    cv.z = acc[i][2] * rq * rk.z;
    cv.w = acc[i][3] * rq * rk.w;
    *(float4*)(cosm + (size_t)(bb + ty * 4 + i) * NPOOL + bp + tx * 4) = cv;
  }
}

// ---------------------------------------------------------------------------
// Top-4 with fp64 refinement. One wave per row:
//  1. fp32 top-8 candidate pool (per-lane sort-8 + xor-butterfly bitonic merge)
//  2. rescore the 8 candidates in fp64 (cooperative dot across the wave)
//  3. pick top-4 by fp64 value (tie -> lower index), write kidx + counts
// fp32 cos noise ~1e-7 vs rank-4/5 gaps ~1e-4: top-8 membership is safe.
// ---------------------------------------------------------------------------
__device__ __forceinline__ bool btf(float av, int ai, float bv, int bi) {
  return (av > bv) || (av == bv && ai < bi);
}
__device__ __forceinline__ bool btd(double av, int ai, double bv, int bi) {
  return (av > bv) || (av == bv && ai < bi);
}
#define CE(a, b)                                                        \
  do {                                                                  \
    if (!btf(v[a], vi[a], v[b], vi[b])) {                               \
      float tv = v[a]; v[a] = v[b]; v[b] = tv;                          \
      int ti = vi[a]; vi[a] = vi[b]; vi[b] = ti;                        \
    }                                                                   \
  } while (0)

__global__ __launch_bounds__(256) void topk_kernel(
    const float* __restrict__ cosm, const float* __restrict__ xq,
    const float* __restrict__ ek, const double* __restrict__ qn,
    const double* __restrict__ kn, int* __restrict__ kidx,
    int* __restrict__ counts) {
  int wave = threadIdx.x >> 6, lane = threadIdx.x & 63;
  int row = blockIdx.x * 4 + wave;
  const float* crow = cosm + (size_t)row * NPOOL;
  float v[8]; int vi[8];
#pragma unroll
  for (int j = 0; j < 8; j++) {
    int p = j * 64 + lane;
    v[j] = crow[p];
    vi[j] = p;
  }
  // sort-8 descending (Batcher odd-even mergesort, 19 CEs)
  CE(0,1); CE(2,3); CE(4,5); CE(6,7);
  CE(0,2); CE(1,3); CE(4,6); CE(5,7);
  CE(1,2); CE(5,6);
  CE(0,4); CE(1,5); CE(2,6); CE(3,7);
  CE(2,4); CE(3,5);
  CE(1,2); CE(3,4); CE(5,6);
  // butterfly merge: after 6 rounds every lane holds the global top-8
#pragma unroll
  for (int off = 1; off < 64; off <<= 1) {
    float ov[8]; int oi[8];
#pragma unroll
    for (int m = 0; m < 8; m++) {
      ov[m] = __shfl_xor(v[m], off, 64);
      oi[m] = __shfl_xor(vi[m], off, 64);
    }
    // pairwise top-8 of two sorted-desc lists -> bitonic
#pragma unroll
    for (int m = 0; m < 8; m++) {
      if (!btf(v[m], vi[m], ov[7 - m], oi[7 - m])) { v[m] = ov[7 - m]; vi[m] = oi[7 - m]; }
    }
    // bitonic sort-8 descending (3 stages)
    CE(0,4); CE(1,5); CE(2,6); CE(3,7);
    CE(0,2); CE(1,3); CE(4,6); CE(5,7);
    CE(0,1); CE(2,3); CE(4,5); CE(6,7);
  }
  // fp64 rescore of the 8 candidates (wave-cooperative dot, 12 elems/lane)
  const float* xrow = xq + (size_t)row * NEMB;
  double xr[12];
#pragma unroll
  for (int e = 0; e < 12; e++) xr[e] = (double)xrow[lane * 12 + e];
  double qmax = fmax(qn[row], 1e-12);
  double cand[8];
#pragma unroll
  for (int c = 0; c < 8; c++) {
    int pi = vi[c];
    const float* kb = ek + (size_t)pi * NEMB + lane * 12;
    double s = 0.0;
#pragma unroll
    for (int e = 0; e < 12; e++) s = fma(xr[e], (double)kb[e], s);
#pragma unroll
    for (int off = 1; off < 64; off <<= 1) s += __shfl_xor(s, off, 64);
    cand[c] = s / (qmax * fmax(kn[pi], 1e-12));
  }
  // top-4 of 8 by fp64 (uniform across lanes; lane 0 writes)
  bool used[8] = {false, false, false, false, false, false, false, false};
#pragma unroll
  for (int m = 0; m < NTOPK; m++) {
    int best = -1;
#pragma unroll
    for (int c = 0; c < 8; c++) {
      if (!used[c] && (best < 0 || btd(cand[c], vi[c], cand[best], vi[best]))) best = c;
    }
    used[best] = true;
    if (lane == 0) {
      kidx[row * 4 + m] = vi[best];
      atomicAdd(&counts[vi[best]], 1);
    }
  }
}
#undef CE

// ---------------------------------------------------------------------------
// Column sums S[p] = sum_b cos[b][p] (fp64 accum over fp32 cosm)
// ---------------------------------------------------------------------------
__global__ __launch_bounds__(256) void colsum_kernel(
    const float* __restrict__ cosm, double* __restrict__ S) {
  int p = blockIdx.x * 256 + threadIdx.x;
  int r0 = blockIdx.y * 128;
  double s = 0.0;
  for (int r = r0; r < r0 + 128; r++) s += (double)cosm[(size_t)r * NPOOL + p];
  atomicAdd(&S[p], s);
}

// ---------------------------------------------------------------------------
// loss = 1 - (sum_p counts[p]*S[p]) / (B*B*K); also emit counts as float
// ---------------------------------------------------------------------------
__global__ __launch_bounds__(256) void loss_counts_kernel(
    const double* __restrict__ S, const int* __restrict__ counts,
    float* __restrict__ out_loss, float* __restrict__ out_counts) {
  double s = 0.0;
  for (int p = threadIdx.x; p < NPOOL; p += 256) {
    int c = counts[p];
    out_counts[p] = (float)c;
    s += (double)c * S[p];
  }
  for (int off = 32; off > 0; off >>= 1) s += __shfl_down(s, off, 64);
  __shared__ double red[4];
  if ((threadIdx.x & 63) == 0) red[threadIdx.x >> 6] = s;
  __syncthreads();
  if (threadIdx.x == 0) {
    double total = red[0] + red[1] + red[2] + red[3];
    *out_loss = (float)(1.0 - total / (double)((long long)NB * NB * NTOPK));
  }
}

// ---------------------------------------------------------------------------
// Gather Pk/Pv (float4, coalesced) + fused x_block passthrough.
// slot s<16 -> e_p[idx[s/4]][s%4 (+4 for Pv)]; s>=16 -> g_p
// ---------------------------------------------------------------------------
__global__ __launch_bounds__(256) void gather_kernel(
    const float* __restrict__ e_p, const float* __restrict__ g_p,
    const int* __restrict__ kidx, const float* __restrict__ x_block,
    float* __restrict__ Pk, float* __restrict__ Pv,
    float* __restrict__ out_xb) {
  int b = blockIdx.x;
  __shared__ int idx[4];
  if (threadIdx.x < 4) idx[threadIdx.x] = kidx[b * 4 + threadIdx.x];
  __syncthreads();
  float4* dk = (float4*)(Pk + (size_t)b * NSLOT * NEMB);
  float4* dv = (float4*)(Pv + (size_t)b * NSLOT * NEMB);
  const int R = NEMB / 4;  // 192 float4 per row
  for (int u = threadIdx.x; u < NSLOT * R; u += 256) {
    int s = u / R;
    int r = u - s * R;
    const float4* sk;
    const float4* sv;
    if (s < 16) {
      int pi = idx[s >> 2];
      int t = s & 3;
      const float* basek = e_p + ((size_t)pi * NEPL + t) * NEMB;
      sk = (const float4*)basek;
      sv = (const float4*)(basek + 4 * NEMB);
    } else {
      sk = (const float4*)(g_p + (size_t)(s - 16) * NEMB);
      sv = (const float4*)(g_p + (size_t)(s - 16 + 4) * NEMB);
    }
    dk[u] = sk[r];
    dv[u] = sv[r];
  }
  // fused x_block passthrough (dst unaligned for float4 -> scalar)
  for (int i = threadIdx.x; i < NEMB; i += 256)
    out_xb[(size_t)b * NEMB + i] = x_block[(size_t)b * NEMB + i];
}

extern "C" void kernel_launch(void* const* d_in, const int* in_sizes, int n_in,
                              void* d_out, int out_size, void* d_ws, size_t ws_size,
                              hipStream_t stream) {
  const float* x_querry = (const float*)d_in[0];
  const float* x_block  = (const float*)d_in[1];
  const float* e_k      = (const float*)d_in[2];
  const float* e_p      = (const float*)d_in[3];
  const float* g_p      = (const float*)d_in[4];
  // d_in[5] = l (scalar 0) — both E- and G-branches always taken.

  // Workspace layout (~4.3 MB)
  double* qn     = (double*)d_ws;                    // 2048
  double* kn     = qn + NB;                          // 512
  double* S      = kn + NPOOL;                       // 512
  float*  rqn    = (float*)(S + NPOOL);              // 2048
  float*  rkn    = rqn + NB;                         // 512
  float*  cosm   = rkn + NPOOL;                      // 2048*512 (16B-aligned)
  int*    kidx   = (int*)(cosm + (size_t)NB * NPOOL);// 8192
  int*    counts = kidx + NB * NTOPK;                // 512

  // Output layout (floats): Pk | Pv | loss | counts | x_block
  float* out        = (float*)d_out;
  float* Pk         = out;
  float* Pv         = Pk + (size_t)NB * NSLOT * NEMB;
  float* out_loss   = Pv + (size_t)NB * NSLOT * NEMB;
  float* out_counts = out_loss + 1;
  float* out_xb     = out_counts + NPOOL;

  hipMemsetAsync(S, 0, NPOOL * sizeof(double), stream);
  hipMemsetAsync(counts, 0, NPOOL * sizeof(int), stream);

  norms_kernel<<<NB + NPOOL, 256, 0, stream>>>(x_querry, e_k, qn, kn, rqn, rkn);
  cos_kernel<<<dim3(NPOOL / 64, NB / 64), 256, 0, stream>>>(x_querry, e_k, rqn, rkn, cosm);
  topk_kernel<<<NB / 4, 256, 0, stream>>>(cosm, x_querry, e_k, qn, kn, kidx, counts);
  colsum_kernel<<<dim3(NPOOL / 256, NB / 128), 256, 0, stream>>>(cosm, S);
  loss_counts_kernel<<<1, 256, 0, stream>>>(S, counts, out_loss, out_counts);
  gather_kernel<<<NB, 256, 0, stream>>>(e_p, g_p, kidx, x_block, Pk, Pv, out_xb);
}